// Round 5
// baseline (133.055 us; speedup 1.0000x reference)
//
#include <hip/hip_runtime.h>

// CBOWSubword: out[t,:] = W[seq[t],:] + W[pre[t],:] + W[post[t],:]
// B*S = 131072 tokens, D = 128 fp32 (= 32 float4 per row).
//
// R3 state: gather kernel is BW-limited at 3.85 TB/s total traffic
// (FETCH 94.4 MB random 512B reads + 64 MiB streaming write in ~42.8us);
// concurrency ruled out (2-tok MLP flat). Poison fill flushes L3 every
// iteration, so the random gather's cross-XCD duplicate fetches hit DRAM
// with row-miss penalties.
// R4: warm the 51.2 MB table into Infinity Cache (MALL, memory-side,
// allocates on read) with a SEQUENTIAL streaming pass (~8us at 6.4TB/s),
// then run the gather: random reads become L3 hits, DRAM sees only the
// streaming write. Two launches on one stream = clean phase barrier.

#define D4 32              // 128 floats / 4 per float4
#define VOCAB_VEC 3200000  // 100000 rows * 32 float4

__global__ __launch_bounds__(256) void warm_l3_kernel(
    const float4* __restrict__ w, int n_vec)
{
    int i = blockIdx.x * blockDim.x + threadIdx.x;
    int stride = gridDim.x * blockDim.x;
    for (; i < n_vec; i += stride) {
        float4 v = w[i];
        // Keep the load live without any store (rule: ablation-via-skip DCE).
        asm volatile("" :: "v"(v.x), "v"(v.y), "v"(v.z), "v"(v.w));
    }
}

__global__ __launch_bounds__(256) void cbow_gather3_kernel(
    const int* __restrict__ seq,
    const int* __restrict__ pre,
    const int* __restrict__ post,
    const float4* __restrict__ weight,
    float4* __restrict__ out,
    int n_tokens)
{
    int tid  = blockIdx.x * blockDim.x + threadIdx.x;
    int pair = tid >> 5;       // each 32-lane group handles tokens 2k, 2k+1
    int lane = tid & 31;       // which float4 of the 128-float row
    int t0 = pair * 2;
    if (t0 >= n_tokens) return;
    int t1 = t0 + 1;           // n_tokens is even (131072)

    int s0 = seq[t0], p0 = pre[t0], q0 = post[t0];
    int s1 = seq[t1], p1 = pre[t1], q1 = post[t1];

    float4 a0 = weight[(size_t)s0 * D4 + lane];
    float4 b0 = weight[(size_t)p0 * D4 + lane];
    float4 c0 = weight[(size_t)q0 * D4 + lane];
    float4 a1 = weight[(size_t)s1 * D4 + lane];
    float4 b1 = weight[(size_t)p1 * D4 + lane];
    float4 c1 = weight[(size_t)q1 * D4 + lane];

    float4 r0, r1;
    r0.x = a0.x + b0.x + c0.x;  r0.y = a0.y + b0.y + c0.y;
    r0.z = a0.z + b0.z + c0.z;  r0.w = a0.w + b0.w + c0.w;
    r1.x = a1.x + b1.x + c1.x;  r1.y = a1.y + b1.y + c1.y;
    r1.z = a1.z + b1.z + c1.z;  r1.w = a1.w + b1.w + c1.w;

    out[(size_t)t0 * D4 + lane] = r0;
    out[(size_t)t1 * D4 + lane] = r1;
}

extern "C" void kernel_launch(void* const* d_in, const int* in_sizes, int n_in,
                              void* d_out, int out_size, void* d_ws, size_t ws_size,
                              hipStream_t stream)
{
    const int*    seq    = (const int*)d_in[0];
    const int*    pre    = (const int*)d_in[1];
    const int*    post   = (const int*)d_in[2];
    const float4* weight = (const float4*)d_in[3];
    float4*       out    = (float4*)d_out;

    const int n_tokens = in_sizes[0];          // 128*1024 = 131072

    // Phase 1: sequential stream of the whole table -> allocate in L3.
    warm_l3_kernel<<<2048, 256, 0, stream>>>(weight, VOCAB_VEC);

    // Phase 2: gather (stream-ordered after phase 1).
    const long n_pairs = (n_tokens + 1) / 2;
    const long total_threads = n_pairs * 32;
    const int block = 256;
    const int grid = (int)((total_threads + block - 1) / block);
    cbow_gather3_kernel<<<grid, block, 0, stream>>>(seq, pre, post, weight, out, n_tokens);
}

// Round 6
// 125.476 us; speedup vs baseline: 1.0604x; 1.0604x over previous
//
#include <hip/hip_runtime.h>

// CBOWSubword: out[t,:] = W[seq[t],:] + W[pre[t],:] + W[post[t],:]
// B*S = 131072 tokens, D = 128 fp32 (= 32 float4 per row).
//
// FINAL (revert to R3-best). Ledger of tested theories:
//  - NT stores + NT index loads: FETCH flat (95.9->94.5 MB), dur +5% -> reverted.
//  - 2 tokens/thread ILP (kept, harmless): dur flat -> not latency-limited.
//  - L3 pre-warm pass: net +7.5us -> L3 residency doesn't fix random-512B
//    gather; reverted.
// FETCH_SIZE pinned at ~94.4 MB (vs 53 MB ideal) across all variants =
// structural cross-XCD L2 duplication of randomly-shared rows. Floor:
// 94 MB random-512B read + 67 MB streaming write at ~60% mixed-pattern
// HBM efficiency ~= 42 us, which this kernel achieves.

#define D4 32  // 128 floats / 4 per float4

__global__ __launch_bounds__(256) void cbow_gather3_kernel(
    const int* __restrict__ seq,
    const int* __restrict__ pre,
    const int* __restrict__ post,
    const float4* __restrict__ weight,
    float4* __restrict__ out,
    int n_tokens)
{
    int tid  = blockIdx.x * blockDim.x + threadIdx.x;
    int pair = tid >> 5;       // each 32-lane group handles tokens 2k, 2k+1
    int lane = tid & 31;       // which float4 of the 128-float row
    int t0 = pair * 2;
    if (t0 >= n_tokens) return;
    int t1 = t0 + 1;           // n_tokens is even (131072)

    int s0 = seq[t0], p0 = pre[t0], q0 = post[t0];
    int s1 = seq[t1], p1 = pre[t1], q1 = post[t1];

    float4 a0 = weight[(size_t)s0 * D4 + lane];
    float4 b0 = weight[(size_t)p0 * D4 + lane];
    float4 c0 = weight[(size_t)q0 * D4 + lane];
    float4 a1 = weight[(size_t)s1 * D4 + lane];
    float4 b1 = weight[(size_t)p1 * D4 + lane];
    float4 c1 = weight[(size_t)q1 * D4 + lane];

    float4 r0, r1;
    r0.x = a0.x + b0.x + c0.x;  r0.y = a0.y + b0.y + c0.y;
    r0.z = a0.z + b0.z + c0.z;  r0.w = a0.w + b0.w + c0.w;
    r1.x = a1.x + b1.x + c1.x;  r1.y = a1.y + b1.y + c1.y;
    r1.z = a1.z + b1.z + c1.z;  r1.w = a1.w + b1.w + c1.w;

    out[(size_t)t0 * D4 + lane] = r0;
    out[(size_t)t1 * D4 + lane] = r1;
}

extern "C" void kernel_launch(void* const* d_in, const int* in_sizes, int n_in,
                              void* d_out, int out_size, void* d_ws, size_t ws_size,
                              hipStream_t stream)
{
    const int*    seq    = (const int*)d_in[0];
    const int*    pre    = (const int*)d_in[1];
    const int*    post   = (const int*)d_in[2];
    const float4* weight = (const float4*)d_in[3];
    float4*       out    = (float4*)d_out;

    const int n_tokens = in_sizes[0];          // 128*1024 = 131072
    const long n_pairs = (n_tokens + 1) / 2;
    const long total_threads = n_pairs * 32;
    const int block = 256;
    const int grid = (int)((total_threads + block - 1) / block);

    cbow_gather3_kernel<<<grid, block, 0, stream>>>(seq, pre, post, weight, out, n_tokens);
}